// Round 8
// baseline (761.091 us; speedup 1.0000x reference)
//
#include <hip/hip_runtime.h>
#include <math.h>

#define HID   1024
#define OUTD  8192
#define NSUBJ 8
#define BATCH 64
#define TLEN  512

// ws layout (float offsets) — round-4 layout
#define OFF_PP    0u           // pool partials: 16*64*1024 = 1048576
#define OFF_P1    1048576u     // mlp1 partials: 32*64*1024 = 2097152
#define OFF_P2    3145728u     // mlp2 partials: 32*64*1024
#define OFF_H     5242880u     // 64*1024
#define OFF_MUP   5308416u     // mu partials: 8*64*8192 = 4194304
#define OFF_LVP   9502720u     // lv partials: 8*64*8192

// ================= DIAGNOSTIC: pool x8 (bijective tc shift per rep) ================
__global__ __launch_bounds__(256) void k_pool_diag(const float* __restrict__ ctx,
                                                   float* __restrict__ pp) {
    int b = blockIdx.x;   // 64
    int hid = threadIdx.x * 4;
    for (int r = 0; r < 8; ++r) {
        int tc = (blockIdx.y + r) & 15;   // 16 chunks, bijective per rep
        const float* base = ctx + ((size_t)b * TLEN + (size_t)tc * 32) * HID + hid;
        float4 acc = make_float4(0.f, 0.f, 0.f, 0.f);
#pragma unroll 8
        for (int t = 0; t < 32; ++t) {
            float4 v = *(const float4*)(base + (size_t)t * HID);
            acc.x += v.x; acc.y += v.y; acc.z += v.z; acc.w += v.w;
        }
        *(float4*)(pp + ((size_t)tc * BATCH + b) * HID + hid) = acc;
    }
}

// -------- MLP layer 1: fused pool-reduce (LDS x-tile) + GEMM partial (r4) --------
__global__ __launch_bounds__(256) void k_mlp1(const float* __restrict__ pp,
                                              const float* __restrict__ w1,
                                              float* __restrict__ p1) {
    __shared__ float xs[32][34];
    int j  = blockIdx.x * 256 + threadIdx.x;  // 4 jchunks
    int k0 = blockIdx.y * 32;                 // 32 kchunks
    int b0 = blockIdx.z * 32;                 // 2 bgroups
    {
        int bb = threadIdx.x >> 3;
        int kk = (threadIdx.x & 7) * 4;
        float4 s = make_float4(0.f, 0.f, 0.f, 0.f);
#pragma unroll
        for (int tc = 0; tc < 16; ++tc) {
            float4 v = *(const float4*)(pp + (size_t)tc * 65536 + (b0 + bb) * 1024 + k0 + kk);
            s.x += v.x; s.y += v.y; s.z += v.z; s.w += v.w;
        }
        const float inv = 1.0f / 512.0f;
        xs[bb][kk]     = s.x * inv;
        xs[bb][kk + 1] = s.y * inv;
        xs[bb][kk + 2] = s.z * inv;
        xs[bb][kk + 3] = s.w * inv;
    }
    __syncthreads();
    float acc[32];
#pragma unroll
    for (int i = 0; i < 32; ++i) acc[i] = 0.f;
    for (int kk = 0; kk < 32; kk += 2) {
        float wa = w1[(size_t)(k0 + kk) * HID + j];
        float wb = w1[(size_t)(k0 + kk + 1) * HID + j];
#pragma unroll
        for (int i = 0; i < 32; ++i) {
            acc[i] = fmaf(xs[i][kk], wa, acc[i]);
            acc[i] = fmaf(xs[i][kk + 1], wb, acc[i]);
        }
    }
    float* dst = p1 + (size_t)blockIdx.y * 65536;
#pragma unroll
    for (int i = 0; i < 32; ++i) dst[(b0 + i) * 1024 + j] = acc[i];
}

// -------- MLP layer 2: fused reduce+bias+exact-GELU + GEMM partial (r4) --------
__global__ __launch_bounds__(256) void k_mlp2(const float* __restrict__ p1,
                                              const float* __restrict__ b1,
                                              const float* __restrict__ w2,
                                              float* __restrict__ p2) {
    __shared__ float xs[32][34];
    int j  = blockIdx.x * 256 + threadIdx.x;
    int k0 = blockIdx.y * 32;
    int b0 = blockIdx.z * 32;
    {
        int bb = threadIdx.x >> 3;
        int kk = (threadIdx.x & 7) * 4;
        float4 s = make_float4(0.f, 0.f, 0.f, 0.f);
#pragma unroll
        for (int kc = 0; kc < 32; ++kc) {
            float4 v = *(const float4*)(p1 + (size_t)kc * 65536 + (b0 + bb) * 1024 + k0 + kk);
            s.x += v.x; s.y += v.y; s.z += v.z; s.w += v.w;
        }
        float4 bbv = *(const float4*)(b1 + k0 + kk);
        s.x += bbv.x; s.y += bbv.y; s.z += bbv.z; s.w += bbv.w;
        const float r = 0.70710678118654752f;
        xs[bb][kk]     = 0.5f * s.x * (1.0f + erff(s.x * r));
        xs[bb][kk + 1] = 0.5f * s.y * (1.0f + erff(s.y * r));
        xs[bb][kk + 2] = 0.5f * s.z * (1.0f + erff(s.z * r));
        xs[bb][kk + 3] = 0.5f * s.w * (1.0f + erff(s.w * r));
    }
    __syncthreads();
    float acc[32];
#pragma unroll
    for (int i = 0; i < 32; ++i) acc[i] = 0.f;
    for (int kk = 0; kk < 32; kk += 2) {
        float wa = w2[(size_t)(k0 + kk) * HID + j];
        float wb = w2[(size_t)(k0 + kk + 1) * HID + j];
#pragma unroll
        for (int i = 0; i < 32; ++i) {
            acc[i] = fmaf(xs[i][kk], wa, acc[i]);
            acc[i] = fmaf(xs[i][kk + 1], wb, acc[i]);
        }
    }
    float* dst = p2 + (size_t)blockIdx.y * 65536;
#pragma unroll
    for (int i = 0; i < 32; ++i) dst[(b0 + i) * 1024 + j] = acc[i];
}

// ---------------- reduce 32 partials + bias -> hbuf (r4) ----------------
__global__ __launch_bounds__(256) void k_red_bias(const float* __restrict__ p,
                                                  const float* __restrict__ bias,
                                                  float* __restrict__ out) {
    int i = (blockIdx.x * 256 + threadIdx.x) * 4;  // 64 blocks
    int j = i & (HID - 1);
    float4 s = make_float4(0.f, 0.f, 0.f, 0.f);
#pragma unroll
    for (int kc = 0; kc < 32; ++kc) {
        float4 v = *(const float4*)(p + (size_t)kc * 65536 + i);
        s.x += v.x; s.y += v.y; s.z += v.z; s.w += v.w;
    }
    float4 bb = *(const float4*)(bias + j);
    s.x += bb.x; s.y += bb.y; s.z += bb.z; s.w += bb.w;
    *(float4*)(out + i) = s;
}

// ---------------- mu tile body: NS samples, k-chunk 128, wv prefetch (r4) ----------
template <int NS>
__device__ __forceinline__ void mu_tile(const float* __restrict__ hmat,
                                        const float* __restrict__ wbase,
                                        float* __restrict__ mup_kc,
                                        const int* bo, int n, int k0, int o) {
    float4 acc[NS];
#pragma unroll
    for (int i = 0; i < NS; ++i) acc[i] = make_float4(0.f, 0.f, 0.f, 0.f);
    float4 wv[4];
#pragma unroll
    for (int kk = 0; kk < 4; ++kk)
        wv[kk] = *(const float4*)(wbase + (size_t)(k0 + kk) * OUTD + o);
    for (int k = k0; k < k0 + 128; k += 4) {
        float4 hv[NS];
#pragma unroll
        for (int i = 0; i < NS; ++i)
            hv[i] = *(const float4*)(hmat + bo[i] * HID + k);
        int kn = (k + 4 < k0 + 128) ? (k + 4) : k0;  // last-iter reload, harmless
        float4 wn[4];
#pragma unroll
        for (int kk = 0; kk < 4; ++kk)
            wn[kk] = *(const float4*)(wbase + (size_t)(kn + kk) * OUTD + o);
#pragma unroll
        for (int kk = 0; kk < 4; ++kk) {
            float4 w = wv[kk];
#pragma unroll
            for (int i = 0; i < NS; ++i) {
                float h = (kk == 0) ? hv[i].x : (kk == 1) ? hv[i].y
                        : (kk == 2) ? hv[i].z : hv[i].w;
                acc[i].x = fmaf(h, w.x, acc[i].x);
                acc[i].y = fmaf(h, w.y, acc[i].y);
                acc[i].z = fmaf(h, w.z, acc[i].z);
                acc[i].w = fmaf(h, w.w, acc[i].w);
            }
        }
#pragma unroll
        for (int kk = 0; kk < 4; ++kk) wv[kk] = wn[kk];
    }
#pragma unroll
    for (int i = 0; i < NS; ++i)
        if (i < n) *(float4*)(mup_kc + (size_t)bo[i] * OUTD + o) = acc[i];
}

// ============ DIAGNOSTIC: mu x4 (bijective kc shift — each rep streams 256 MB) =====
__global__ __launch_bounds__(256) void k_mu_diag(const float* __restrict__ hmat,
                                                 const float* __restrict__ subj_w,
                                                 const int* __restrict__ sid,
                                                 float* __restrict__ mup) {
    int o = blockIdx.x * 1024 + threadIdx.x * 4;   // 8 ochunks
    int s = blockIdx.z;                            // 8 subjects
    int lane = threadIdx.x & 63;
    int mysid = sid[lane];
    unsigned long long m = __ballot(mysid == s);
    int ns = __popcll(m);
    if (ns == 0) return;
    const float* wbase = subj_w + (size_t)s * HID * OUTD;
    for (int r = 0; r < 4; ++r) {
        int kc = ((int)blockIdx.y + r) & 7;        // 8 kchunks, bijective per rep
        int k0 = kc * 128;
        float* mup_kc = mup + (size_t)kc * BATCH * OUTD;
        unsigned long long mm = m;
        for (int base = 0; base < ns; base += 12) {
            int take = ns - base; if (take > 12) take = 12;
            int fb = (int)__builtin_ctzll(mm);
            int bo[12];
#pragma unroll
            for (int i = 0; i < 12; ++i) {
                bo[i] = (mm != 0ull) ? (int)__builtin_ctzll(mm) : fb;
                if (mm != 0ull) mm &= (mm - 1ull);
            }
            if (take <= 4)       mu_tile<4>(hmat, wbase, mup_kc, bo, take, k0, o);
            else if (take <= 8)  mu_tile<8>(hmat, wbase, mup_kc, bo, take, k0, o);
            else                 mu_tile<12>(hmat, wbase, mup_kc, bo, take, k0, o);
        }
    }
}

// ============ DIAGNOSTIC: lv x12 (bijective kc shift) =============================
__global__ __launch_bounds__(256) void k_lv_diag(const float* __restrict__ hmat,
                                                 const float* __restrict__ lv_w,
                                                 float* __restrict__ lvp) {
    int o  = blockIdx.x * 512 + threadIdx.x * 2;  // 16 ochunks
    int b0 = blockIdx.z * 32;                     // 2 bgroups
    for (int r = 0; r < 12; ++r) {
        int kc = ((int)blockIdx.y + r) & 7;       // 8 kchunks, bijective per rep
        int k0 = kc * 128;
        float2 acc[32];
#pragma unroll
        for (int i = 0; i < 32; ++i) acc[i] = make_float2(0.f, 0.f);
        float2 wv0 = *(const float2*)(lv_w + (size_t)k0 * OUTD + o);
        float2 wv1 = *(const float2*)(lv_w + (size_t)(k0 + 1) * OUTD + o);
        for (int k = k0; k < k0 + 128; k += 2) {
            float2 hv[32];
#pragma unroll
            for (int i = 0; i < 32; ++i)
                hv[i] = *(const float2*)(hmat + (b0 + i) * HID + k);
            int kn = (k + 2 < k0 + 128) ? (k + 2) : k0;
            float2 wn0 = *(const float2*)(lv_w + (size_t)kn * OUTD + o);
            float2 wn1 = *(const float2*)(lv_w + (size_t)(kn + 1) * OUTD + o);
#pragma unroll
            for (int i = 0; i < 32; ++i) {
                acc[i].x = fmaf(hv[i].x, wv0.x, acc[i].x);
                acc[i].y = fmaf(hv[i].x, wv0.y, acc[i].y);
                acc[i].x = fmaf(hv[i].y, wv1.x, acc[i].x);
                acc[i].y = fmaf(hv[i].y, wv1.y, acc[i].y);
            }
            wv0 = wn0; wv1 = wn1;
        }
#pragma unroll
        for (int i = 0; i < 32; ++i) {
            float* dst = lvp + ((size_t)kc * BATCH + b0 + i) * OUTD + o;
            dst[0] = acc[i].x; dst[1] = acc[i].y;
        }
    }
}

// ---------------- combine: biases, clip, sample; write x0|mu|log_var (r4) ----------
__global__ __launch_bounds__(256) void k_combine(const float* __restrict__ mup,
                                                 const float* __restrict__ lvp,
                                                 const float* __restrict__ eps,
                                                 const float* __restrict__ subj_b,
                                                 const float* __restrict__ lv_b,
                                                 const int* __restrict__ sid,
                                                 float* __restrict__ out) {
    int idx = (blockIdx.x * 256 + threadIdx.x) * 4;  // over 524288
    int b = idx >> 13;
    int o = idx & (OUTD - 1);
    float4 m = make_float4(0.f, 0.f, 0.f, 0.f);
    float4 l = make_float4(0.f, 0.f, 0.f, 0.f);
#pragma unroll
    for (int kc = 0; kc < 8; ++kc) {
        float4 t = *(const float4*)(mup + (size_t)kc * 524288 + idx);
        m.x += t.x; m.y += t.y; m.z += t.z; m.w += t.w;
        float4 u = *(const float4*)(lvp + (size_t)kc * 524288 + idx);
        l.x += u.x; l.y += u.y; l.z += u.z; l.w += u.w;
    }
    int s = sid[b];
    float4 sb = *(const float4*)(subj_b + s * OUTD + o);
    float4 lb = *(const float4*)(lv_b + o);
    m.x += sb.x; m.y += sb.y; m.z += sb.z; m.w += sb.w;
    l.x = fminf(fmaxf(l.x + lb.x, -10.f), 2.f);
    l.y = fminf(fmaxf(l.y + lb.y, -10.f), 2.f);
    l.z = fminf(fmaxf(l.z + lb.z, -10.f), 2.f);
    l.w = fminf(fmaxf(l.w + lb.w, -10.f), 2.f);
    float4 e = *(const float4*)(eps + idx);
    float4 x0;
    x0.x = m.x + e.x * __expf(0.5f * l.x);
    x0.y = m.y + e.y * __expf(0.5f * l.y);
    x0.z = m.z + e.z * __expf(0.5f * l.z);
    x0.w = m.w + e.w * __expf(0.5f * l.w);
    *(float4*)(out + idx) = x0;
    *(float4*)(out + 524288 + idx) = m;
    *(float4*)(out + 1048576 + idx) = l;
}

extern "C" void kernel_launch(void* const* d_in, const int* in_sizes, int n_in,
                              void* d_out, int out_size, void* d_ws, size_t ws_size,
                              hipStream_t stream) {
    const float* ctx    = (const float*)d_in[0];
    const int*   sid    = (const int*)  d_in[1];
    const float* eps    = (const float*)d_in[2];
    const float* w1     = (const float*)d_in[3];
    const float* b1     = (const float*)d_in[4];
    const float* w2     = (const float*)d_in[5];
    const float* b2     = (const float*)d_in[6];
    const float* subj_w = (const float*)d_in[7];
    const float* subj_b = (const float*)d_in[8];
    const float* lv_w   = (const float*)d_in[9];
    const float* lv_b   = (const float*)d_in[10];
    float* out = (float*)d_out;

    float* ws   = (float*)d_ws;
    float* pp   = ws + OFF_PP;
    float* p1   = ws + OFF_P1;
    float* p2   = ws + OFF_P2;
    float* hbuf = ws + OFF_H;
    float* mup  = ws + OFF_MUP;
    float* lvp  = ws + OFF_LVP;

    k_pool_diag<<<dim3(BATCH, 16), 256, 0, stream>>>(ctx, pp);
    k_mlp1<<<dim3(4, 32, 2), 256, 0, stream>>>(pp, w1, p1);
    k_mlp2<<<dim3(4, 32, 2), 256, 0, stream>>>(p1, b1, w2, p2);
    k_red_bias<<<64, 256, 0, stream>>>(p2, b2, hbuf);
    k_mu_diag<<<dim3(8, 8, NSUBJ), 256, 0, stream>>>(hbuf, subj_w, sid, mup);
    k_lv_diag<<<dim3(16, 8, 2), 256, 0, stream>>>(hbuf, lv_w, lvp);
    k_combine<<<512, 256, 0, stream>>>(mup, lvp, eps, subj_b, lv_b, sid, out);
}

// Round 9
// 190.013 us; speedup vs baseline: 4.0055x; 4.0055x over previous
//
#include <hip/hip_runtime.h>
#include <math.h>

#define HID   1024
#define OUTD  8192
#define NSUBJ 8
#define BATCH 64
#define TLEN  512

// ws layout (float offsets) — round-4 layout
#define OFF_PP    0u           // pool partials: 16*64*1024 = 1048576
#define OFF_P1    1048576u     // mlp1 partials: 32*64*1024 = 2097152
#define OFF_P2    3145728u     // mlp2 partials: 32*64*1024
#define OFF_H     5242880u     // 64*1024
#define OFF_MUP   5308416u     // mu partials: 8*64*8192 = 4194304
#define OFF_LVP   9502720u     // lv partials: 8*64*8192

// ---------------- mean pool: partial sums over 32-t chunks (r4) ----------------
__global__ __launch_bounds__(256) void k_pool(const float* __restrict__ ctx,
                                              float* __restrict__ pp) {
    int b  = blockIdx.x;   // 64
    int tc = blockIdx.y;   // 16
    int hid = threadIdx.x * 4;
    const float* base = ctx + ((size_t)b * TLEN + (size_t)tc * 32) * HID + hid;
    float4 acc = make_float4(0.f, 0.f, 0.f, 0.f);
#pragma unroll 8
    for (int t = 0; t < 32; ++t) {
        float4 v = *(const float4*)(base + (size_t)t * HID);
        acc.x += v.x; acc.y += v.y; acc.z += v.z; acc.w += v.w;
    }
    *(float4*)(pp + ((size_t)tc * BATCH + b) * HID + hid) = acc;
}

// -------- MLP layer 1: fused pool-reduce (LDS x-tile) + GEMM partial, w-prefetch ----
__global__ __launch_bounds__(256) void k_mlp1(const float* __restrict__ pp,
                                              const float* __restrict__ w1,
                                              float* __restrict__ p1) {
    __shared__ float xs[32][34];
    int j  = blockIdx.x * 256 + threadIdx.x;  // 4 jchunks
    int k0 = blockIdx.y * 32;                 // 32 kchunks
    int b0 = blockIdx.z * 32;                 // 2 bgroups
    {
        int bb = threadIdx.x >> 3;
        int kk = (threadIdx.x & 7) * 4;
        float4 s = make_float4(0.f, 0.f, 0.f, 0.f);
#pragma unroll
        for (int tc = 0; tc < 16; ++tc) {
            float4 v = *(const float4*)(pp + (size_t)tc * 65536 + (b0 + bb) * 1024 + k0 + kk);
            s.x += v.x; s.y += v.y; s.z += v.z; s.w += v.w;
        }
        const float inv = 1.0f / 512.0f;
        xs[bb][kk]     = s.x * inv;
        xs[bb][kk + 1] = s.y * inv;
        xs[bb][kk + 2] = s.z * inv;
        xs[bb][kk + 3] = s.w * inv;
    }
    __syncthreads();
    float acc[32];
#pragma unroll
    for (int i = 0; i < 32; ++i) acc[i] = 0.f;
    const float* wp = w1 + (size_t)k0 * HID + j;
    float wa0 = wp[0],        wb0 = wp[HID];
    float wa1 = wp[2 * HID],  wb1 = wp[3 * HID];
#pragma unroll 4
    for (int kk = 0; kk < 32; kk += 2) {
        int kf = kk + 4; if (kf >= 32) kf = 0;
        float wa2 = wp[(size_t)kf * HID];
        float wb2 = wp[(size_t)(kf + 1) * HID];
#pragma unroll
        for (int i = 0; i < 32; ++i) {
            acc[i] = fmaf(xs[i][kk], wa0, acc[i]);
            acc[i] = fmaf(xs[i][kk + 1], wb0, acc[i]);
        }
        wa0 = wa1; wb0 = wb1; wa1 = wa2; wb1 = wb2;
    }
    float* dst = p1 + (size_t)blockIdx.y * 65536;
#pragma unroll
    for (int i = 0; i < 32; ++i) dst[(b0 + i) * 1024 + j] = acc[i];
}

// -------- MLP layer 2: fused reduce+bias+exact-GELU + GEMM partial, w-prefetch ------
__global__ __launch_bounds__(256) void k_mlp2(const float* __restrict__ p1,
                                              const float* __restrict__ b1,
                                              const float* __restrict__ w2,
                                              float* __restrict__ p2) {
    __shared__ float xs[32][34];
    int j  = blockIdx.x * 256 + threadIdx.x;
    int k0 = blockIdx.y * 32;
    int b0 = blockIdx.z * 32;
    {
        int bb = threadIdx.x >> 3;
        int kk = (threadIdx.x & 7) * 4;
        float4 s = make_float4(0.f, 0.f, 0.f, 0.f);
#pragma unroll
        for (int kc = 0; kc < 32; ++kc) {
            float4 v = *(const float4*)(p1 + (size_t)kc * 65536 + (b0 + bb) * 1024 + k0 + kk);
            s.x += v.x; s.y += v.y; s.z += v.z; s.w += v.w;
        }
        float4 bbv = *(const float4*)(b1 + k0 + kk);
        s.x += bbv.x; s.y += bbv.y; s.z += bbv.z; s.w += bbv.w;
        const float r = 0.70710678118654752f;
        xs[bb][kk]     = 0.5f * s.x * (1.0f + erff(s.x * r));
        xs[bb][kk + 1] = 0.5f * s.y * (1.0f + erff(s.y * r));
        xs[bb][kk + 2] = 0.5f * s.z * (1.0f + erff(s.z * r));
        xs[bb][kk + 3] = 0.5f * s.w * (1.0f + erff(s.w * r));
    }
    __syncthreads();
    float acc[32];
#pragma unroll
    for (int i = 0; i < 32; ++i) acc[i] = 0.f;
    const float* wp = w2 + (size_t)k0 * HID + j;
    float wa0 = wp[0],        wb0 = wp[HID];
    float wa1 = wp[2 * HID],  wb1 = wp[3 * HID];
#pragma unroll 4
    for (int kk = 0; kk < 32; kk += 2) {
        int kf = kk + 4; if (kf >= 32) kf = 0;
        float wa2 = wp[(size_t)kf * HID];
        float wb2 = wp[(size_t)(kf + 1) * HID];
#pragma unroll
        for (int i = 0; i < 32; ++i) {
            acc[i] = fmaf(xs[i][kk], wa0, acc[i]);
            acc[i] = fmaf(xs[i][kk + 1], wb0, acc[i]);
        }
        wa0 = wa1; wb0 = wb1; wa1 = wa2; wb1 = wb2;
    }
    float* dst = p2 + (size_t)blockIdx.y * 65536;
#pragma unroll
    for (int i = 0; i < 32; ++i) dst[(b0 + i) * 1024 + j] = acc[i];
}

// ---------------- reduce 32 partials + bias -> hbuf (r4) ----------------
__global__ __launch_bounds__(256) void k_red_bias(const float* __restrict__ p,
                                                  const float* __restrict__ bias,
                                                  float* __restrict__ out) {
    int i = (blockIdx.x * 256 + threadIdx.x) * 4;  // 64 blocks
    int j = i & (HID - 1);
    float4 s = make_float4(0.f, 0.f, 0.f, 0.f);
#pragma unroll
    for (int kc = 0; kc < 32; ++kc) {
        float4 v = *(const float4*)(p + (size_t)kc * 65536 + i);
        s.x += v.x; s.y += v.y; s.z += v.z; s.w += v.w;
    }
    float4 bb = *(const float4*)(bias + j);
    s.x += bb.x; s.y += bb.y; s.z += bb.z; s.w += bb.w;
    *(float4*)(out + i) = s;
}

// ---------------- mu tile body: NS samples, k-chunk 128, wv prefetch (r4) ----------
template <int NS>
__device__ __forceinline__ void mu_tile(const float* __restrict__ hmat,
                                        const float* __restrict__ wbase,
                                        float* __restrict__ mup_kc,
                                        const int* bo, int n, int k0, int o) {
    float4 acc[NS];
#pragma unroll
    for (int i = 0; i < NS; ++i) acc[i] = make_float4(0.f, 0.f, 0.f, 0.f);
    float4 wv[4];
#pragma unroll
    for (int kk = 0; kk < 4; ++kk)
        wv[kk] = *(const float4*)(wbase + (size_t)(k0 + kk) * OUTD + o);
    for (int k = k0; k < k0 + 128; k += 4) {
        float4 hv[NS];
#pragma unroll
        for (int i = 0; i < NS; ++i)
            hv[i] = *(const float4*)(hmat + bo[i] * HID + k);
        int kn = (k + 4 < k0 + 128) ? (k + 4) : k0;  // last-iter reload, harmless
        float4 wn[4];
#pragma unroll
        for (int kk = 0; kk < 4; ++kk)
            wn[kk] = *(const float4*)(wbase + (size_t)(kn + kk) * OUTD + o);
#pragma unroll
        for (int kk = 0; kk < 4; ++kk) {
            float4 w = wv[kk];
#pragma unroll
            for (int i = 0; i < NS; ++i) {
                float h = (kk == 0) ? hv[i].x : (kk == 1) ? hv[i].y
                        : (kk == 2) ? hv[i].z : hv[i].w;
                acc[i].x = fmaf(h, w.x, acc[i].x);
                acc[i].y = fmaf(h, w.y, acc[i].y);
                acc[i].z = fmaf(h, w.z, acc[i].z);
                acc[i].w = fmaf(h, w.w, acc[i].w);
            }
        }
#pragma unroll
        for (int kk = 0; kk < 4; ++kk) wv[kk] = wn[kk];
    }
#pragma unroll
    for (int i = 0; i < NS; ++i)
        if (i < n) *(float4*)(mup_kc + (size_t)bo[i] * OUTD + o) = acc[i];
}

// ------- mu partial: inline ballot grouping, NS-dispatched single-pass tiles (r4) ---
__global__ __launch_bounds__(256) void k_mu(const float* __restrict__ hmat,
                                            const float* __restrict__ subj_w,
                                            const int* __restrict__ sid,
                                            float* __restrict__ mup) {
    int o  = blockIdx.x * 1024 + threadIdx.x * 4;  // 8 ochunks
    int k0 = blockIdx.y * 128;                     // 8 kchunks
    int s  = blockIdx.z;                           // 8 subjects
    int lane = threadIdx.x & 63;
    int mysid = sid[lane];
    unsigned long long m = __ballot(mysid == s);
    int ns = __popcll(m);
    if (ns == 0) return;
    const float* wbase = subj_w + (size_t)s * HID * OUTD;
    float* mup_kc = mup + (size_t)blockIdx.y * BATCH * OUTD;
    unsigned long long mm = m;
    for (int base = 0; base < ns; base += 12) {
        int take = ns - base; if (take > 12) take = 12;
        int fb = (int)__builtin_ctzll(mm);
        int bo[12];
#pragma unroll
        for (int i = 0; i < 12; ++i) {
            bo[i] = (mm != 0ull) ? (int)__builtin_ctzll(mm) : fb;
            if (mm != 0ull) mm &= (mm - 1ull);
        }
        if (take <= 4)       mu_tile<4>(hmat, wbase, mup_kc, bo, take, k0, o);
        else if (take <= 8)  mu_tile<8>(hmat, wbase, mup_kc, bo, take, k0, o);
        else                 mu_tile<12>(hmat, wbase, mup_kc, bo, take, k0, o);
    }
}

// -------- log_var partial: LDS h-tile + 4-stage weight prefetch (NEW) --------------
__global__ __launch_bounds__(256) void k_lv(const float* __restrict__ hmat,
                                            const float* __restrict__ lv_w,
                                            float* __restrict__ lvp) {
    __shared__ float hs[32][132];                 // pad 132: aligned f4, bank-rotated
    int o  = blockIdx.x * 512 + threadIdx.x * 2;  // 16 ochunks
    int k0 = blockIdx.y * 128;                    // 8 kchunks
    int b0 = blockIdx.z * 32;                     // 2 bgroups
    {
        int r = threadIdx.x >> 3;                 // 0..31 sample
        int c = (threadIdx.x & 7) * 16;           // 16 floats each
        const float* src = hmat + (size_t)(b0 + r) * HID + k0 + c;
        float4 v0 = *(const float4*)(src);
        float4 v1 = *(const float4*)(src + 4);
        float4 v2 = *(const float4*)(src + 8);
        float4 v3 = *(const float4*)(src + 12);
        *(float4*)&hs[r][c]      = v0;
        *(float4*)&hs[r][c + 4]  = v1;
        *(float4*)&hs[r][c + 8]  = v2;
        *(float4*)&hs[r][c + 12] = v3;
    }
    __syncthreads();
    float2 acc[32];
#pragma unroll
    for (int i = 0; i < 32; ++i) acc[i] = make_float2(0.f, 0.f);
    const float* wp = lv_w + (size_t)k0 * OUTD + o;
    // 4-stage pipeline: A (in use), B, C in flight
    float2 wA0 = *(const float2*)(wp);
    float2 wA1 = *(const float2*)(wp + OUTD);
    float2 wB0 = *(const float2*)(wp + 2 * (size_t)OUTD);
    float2 wB1 = *(const float2*)(wp + 3 * (size_t)OUTD);
    float2 wC0 = *(const float2*)(wp + 4 * (size_t)OUTD);
    float2 wC1 = *(const float2*)(wp + 5 * (size_t)OUTD);
#pragma unroll 4
    for (int kk = 0; kk < 128; kk += 2) {
        int kf = kk + 6; if (kf >= 128) kf -= 128;   // wrap: harmless reload
        float2 wD0 = *(const float2*)(wp + (size_t)kf * OUTD);
        float2 wD1 = *(const float2*)(wp + (size_t)(kf + 1) * OUTD);
#pragma unroll
        for (int i = 0; i < 32; ++i) {
            float2 h01 = *(const float2*)&hs[i][kk];
            acc[i].x = fmaf(h01.x, wA0.x, acc[i].x);
            acc[i].y = fmaf(h01.x, wA0.y, acc[i].y);
            acc[i].x = fmaf(h01.y, wA1.x, acc[i].x);
            acc[i].y = fmaf(h01.y, wA1.y, acc[i].y);
        }
        wA0 = wB0; wA1 = wB1; wB0 = wC0; wB1 = wC1; wC0 = wD0; wC1 = wD1;
    }
#pragma unroll
    for (int i = 0; i < 32; ++i) {
        float* dst = lvp + ((size_t)blockIdx.y * BATCH + b0 + i) * OUTD + o;
        dst[0] = acc[i].x; dst[1] = acc[i].y;
    }
}

// ---------------- combine: biases, clip, sample; write x0|mu|log_var (r4) ----------
__global__ __launch_bounds__(256) void k_combine(const float* __restrict__ mup,
                                                 const float* __restrict__ lvp,
                                                 const float* __restrict__ eps,
                                                 const float* __restrict__ subj_b,
                                                 const float* __restrict__ lv_b,
                                                 const int* __restrict__ sid,
                                                 float* __restrict__ out) {
    int idx = (blockIdx.x * 256 + threadIdx.x) * 4;  // over 524288
    int b = idx >> 13;
    int o = idx & (OUTD - 1);
    float4 m = make_float4(0.f, 0.f, 0.f, 0.f);
    float4 l = make_float4(0.f, 0.f, 0.f, 0.f);
#pragma unroll
    for (int kc = 0; kc < 8; ++kc) {
        float4 t = *(const float4*)(mup + (size_t)kc * 524288 + idx);
        m.x += t.x; m.y += t.y; m.z += t.z; m.w += t.w;
        float4 u = *(const float4*)(lvp + (size_t)kc * 524288 + idx);
        l.x += u.x; l.y += u.y; l.z += u.z; l.w += u.w;
    }
    int s = sid[b];
    float4 sb = *(const float4*)(subj_b + s * OUTD + o);
    float4 lb = *(const float4*)(lv_b + o);
    m.x += sb.x; m.y += sb.y; m.z += sb.z; m.w += sb.w;
    l.x = fminf(fmaxf(l.x + lb.x, -10.f), 2.f);
    l.y = fminf(fmaxf(l.y + lb.y, -10.f), 2.f);
    l.z = fminf(fmaxf(l.z + lb.z, -10.f), 2.f);
    l.w = fminf(fmaxf(l.w + lb.w, -10.f), 2.f);
    float4 e = *(const float4*)(eps + idx);
    float4 x0;
    x0.x = m.x + e.x * __expf(0.5f * l.x);
    x0.y = m.y + e.y * __expf(0.5f * l.y);
    x0.z = m.z + e.z * __expf(0.5f * l.z);
    x0.w = m.w + e.w * __expf(0.5f * l.w);
    *(float4*)(out + idx) = x0;
    *(float4*)(out + 524288 + idx) = m;
    *(float4*)(out + 1048576 + idx) = l;
}

extern "C" void kernel_launch(void* const* d_in, const int* in_sizes, int n_in,
                              void* d_out, int out_size, void* d_ws, size_t ws_size,
                              hipStream_t stream) {
    const float* ctx    = (const float*)d_in[0];
    const int*   sid    = (const int*)  d_in[1];
    const float* eps    = (const float*)d_in[2];
    const float* w1     = (const float*)d_in[3];
    const float* b1     = (const float*)d_in[4];
    const float* w2     = (const float*)d_in[5];
    const float* b2     = (const float*)d_in[6];
    const float* subj_w = (const float*)d_in[7];
    const float* subj_b = (const float*)d_in[8];
    const float* lv_w   = (const float*)d_in[9];
    const float* lv_b   = (const float*)d_in[10];
    float* out = (float*)d_out;

    float* ws   = (float*)d_ws;
    float* pp   = ws + OFF_PP;
    float* p1   = ws + OFF_P1;
    float* p2   = ws + OFF_P2;
    float* hbuf = ws + OFF_H;
    float* mup  = ws + OFF_MUP;
    float* lvp  = ws + OFF_LVP;

    k_pool<<<dim3(BATCH, 16), 256, 0, stream>>>(ctx, pp);
    k_mlp1<<<dim3(4, 32, 2), 256, 0, stream>>>(pp, w1, p1);
    k_mlp2<<<dim3(4, 32, 2), 256, 0, stream>>>(p1, b1, w2, p2);
    k_red_bias<<<64, 256, 0, stream>>>(p2, b2, hbuf);
    k_mu<<<dim3(8, 8, NSUBJ), 256, 0, stream>>>(hbuf, subj_w, sid, mup);
    k_lv<<<dim3(16, 8, 2), 256, 0, stream>>>(hbuf, lv_w, lvp);
    k_combine<<<512, 256, 0, stream>>>(mup, lvp, eps, subj_b, lv_b, sid, out);
}

// Round 10
// 177.789 us; speedup vs baseline: 4.2809x; 1.0688x over previous
//
#include <hip/hip_runtime.h>
#include <math.h>

#define HID   1024
#define OUTD  8192
#define NSUBJ 8
#define BATCH 64
#define TLEN  512

// ws layout (float offsets)
#define OFF_PP    0u           // pool partials: 16*64*1024 = 1048576
#define OFF_P1    1048576u     // mlp1 partials: 32*64*1024 = 2097152
#define OFF_P2    3145728u     // mlp2 partials: 32*64*1024
#define OFF_H     5242880u     // 64*1024
#define OFF_MUP   5308416u     // mu partials: 8*64*8192 = 4194304
#define OFF_LVP   9502720u     // lv partials: 16*64*8192 = 8388608

// ---------------- mean pool: partial sums over 32-t chunks (r4) ----------------
__global__ __launch_bounds__(256) void k_pool(const float* __restrict__ ctx,
                                              float* __restrict__ pp) {
    int b  = blockIdx.x;   // 64
    int tc = blockIdx.y;   // 16
    int hid = threadIdx.x * 4;
    const float* base = ctx + ((size_t)b * TLEN + (size_t)tc * 32) * HID + hid;
    float4 acc = make_float4(0.f, 0.f, 0.f, 0.f);
#pragma unroll 8
    for (int t = 0; t < 32; ++t) {
        float4 v = *(const float4*)(base + (size_t)t * HID);
        acc.x += v.x; acc.y += v.y; acc.z += v.z; acc.w += v.w;
    }
    *(float4*)(pp + ((size_t)tc * BATCH + b) * HID + hid) = acc;
}

// -------- MLP layer 1: fused pool-reduce (LDS x-tile) + GEMM partial (r4 exact) -----
__global__ __launch_bounds__(256) void k_mlp1(const float* __restrict__ pp,
                                              const float* __restrict__ w1,
                                              float* __restrict__ p1) {
    __shared__ float xs[32][34];
    int j  = blockIdx.x * 256 + threadIdx.x;  // 4 jchunks
    int k0 = blockIdx.y * 32;                 // 32 kchunks
    int b0 = blockIdx.z * 32;                 // 2 bgroups
    {
        int bb = threadIdx.x >> 3;
        int kk = (threadIdx.x & 7) * 4;
        float4 s = make_float4(0.f, 0.f, 0.f, 0.f);
#pragma unroll
        for (int tc = 0; tc < 16; ++tc) {
            float4 v = *(const float4*)(pp + (size_t)tc * 65536 + (b0 + bb) * 1024 + k0 + kk);
            s.x += v.x; s.y += v.y; s.z += v.z; s.w += v.w;
        }
        const float inv = 1.0f / 512.0f;
        xs[bb][kk]     = s.x * inv;
        xs[bb][kk + 1] = s.y * inv;
        xs[bb][kk + 2] = s.z * inv;
        xs[bb][kk + 3] = s.w * inv;
    }
    __syncthreads();
    float acc[32];
#pragma unroll
    for (int i = 0; i < 32; ++i) acc[i] = 0.f;
    for (int kk = 0; kk < 32; kk += 2) {
        float wa = w1[(size_t)(k0 + kk) * HID + j];
        float wb = w1[(size_t)(k0 + kk + 1) * HID + j];
#pragma unroll
        for (int i = 0; i < 32; ++i) {
            acc[i] = fmaf(xs[i][kk], wa, acc[i]);
            acc[i] = fmaf(xs[i][kk + 1], wb, acc[i]);
        }
    }
    float* dst = p1 + (size_t)blockIdx.y * 65536;
#pragma unroll
    for (int i = 0; i < 32; ++i) dst[(b0 + i) * 1024 + j] = acc[i];
}

// -------- MLP layer 2: fused reduce+bias+exact-GELU + GEMM partial (r4 exact) -------
__global__ __launch_bounds__(256) void k_mlp2(const float* __restrict__ p1,
                                              const float* __restrict__ b1,
                                              const float* __restrict__ w2,
                                              float* __restrict__ p2) {
    __shared__ float xs[32][34];
    int j  = blockIdx.x * 256 + threadIdx.x;
    int k0 = blockIdx.y * 32;
    int b0 = blockIdx.z * 32;
    {
        int bb = threadIdx.x >> 3;
        int kk = (threadIdx.x & 7) * 4;
        float4 s = make_float4(0.f, 0.f, 0.f, 0.f);
#pragma unroll
        for (int kc = 0; kc < 32; ++kc) {
            float4 v = *(const float4*)(p1 + (size_t)kc * 65536 + (b0 + bb) * 1024 + k0 + kk);
            s.x += v.x; s.y += v.y; s.z += v.z; s.w += v.w;
        }
        float4 bbv = *(const float4*)(b1 + k0 + kk);
        s.x += bbv.x; s.y += bbv.y; s.z += bbv.z; s.w += bbv.w;
        const float r = 0.70710678118654752f;
        xs[bb][kk]     = 0.5f * s.x * (1.0f + erff(s.x * r));
        xs[bb][kk + 1] = 0.5f * s.y * (1.0f + erff(s.y * r));
        xs[bb][kk + 2] = 0.5f * s.z * (1.0f + erff(s.z * r));
        xs[bb][kk + 3] = 0.5f * s.w * (1.0f + erff(s.w * r));
    }
    __syncthreads();
    float acc[32];
#pragma unroll
    for (int i = 0; i < 32; ++i) acc[i] = 0.f;
    for (int kk = 0; kk < 32; kk += 2) {
        float wa = w2[(size_t)(k0 + kk) * HID + j];
        float wb = w2[(size_t)(k0 + kk + 1) * HID + j];
#pragma unroll
        for (int i = 0; i < 32; ++i) {
            acc[i] = fmaf(xs[i][kk], wa, acc[i]);
            acc[i] = fmaf(xs[i][kk + 1], wb, acc[i]);
        }
    }
    float* dst = p2 + (size_t)blockIdx.y * 65536;
#pragma unroll
    for (int i = 0; i < 32; ++i) dst[(b0 + i) * 1024 + j] = acc[i];
}

// ---------------- reduce 32 partials + bias -> hbuf (r4) ----------------
__global__ __launch_bounds__(256) void k_red_bias(const float* __restrict__ p,
                                                  const float* __restrict__ bias,
                                                  float* __restrict__ out) {
    int i = (blockIdx.x * 256 + threadIdx.x) * 4;  // 64 blocks
    int j = i & (HID - 1);
    float4 s = make_float4(0.f, 0.f, 0.f, 0.f);
#pragma unroll
    for (int kc = 0; kc < 32; ++kc) {
        float4 v = *(const float4*)(p + (size_t)kc * 65536 + i);
        s.x += v.x; s.y += v.y; s.z += v.z; s.w += v.w;
    }
    float4 bb = *(const float4*)(bias + j);
    s.x += bb.x; s.y += bb.y; s.z += bb.z; s.w += bb.w;
    *(float4*)(out + i) = s;
}

// ---------------- mu tile body: NS samples, k-chunk 128, wv prefetch (r4) ----------
template <int NS>
__device__ __forceinline__ void mu_tile(const float* __restrict__ hmat,
                                        const float* __restrict__ wbase,
                                        float* __restrict__ mup_kc,
                                        const int* bo, int n, int k0, int o) {
    float4 acc[NS];
#pragma unroll
    for (int i = 0; i < NS; ++i) acc[i] = make_float4(0.f, 0.f, 0.f, 0.f);
    float4 wv[4];
#pragma unroll
    for (int kk = 0; kk < 4; ++kk)
        wv[kk] = *(const float4*)(wbase + (size_t)(k0 + kk) * OUTD + o);
    for (int k = k0; k < k0 + 128; k += 4) {
        float4 hv[NS];
#pragma unroll
        for (int i = 0; i < NS; ++i)
            hv[i] = *(const float4*)(hmat + bo[i] * HID + k);
        int kn = (k + 4 < k0 + 128) ? (k + 4) : k0;  // last-iter reload, harmless
        float4 wn[4];
#pragma unroll
        for (int kk = 0; kk < 4; ++kk)
            wn[kk] = *(const float4*)(wbase + (size_t)(kn + kk) * OUTD + o);
#pragma unroll
        for (int kk = 0; kk < 4; ++kk) {
            float4 w = wv[kk];
#pragma unroll
            for (int i = 0; i < NS; ++i) {
                float h = (kk == 0) ? hv[i].x : (kk == 1) ? hv[i].y
                        : (kk == 2) ? hv[i].z : hv[i].w;
                acc[i].x = fmaf(h, w.x, acc[i].x);
                acc[i].y = fmaf(h, w.y, acc[i].y);
                acc[i].z = fmaf(h, w.z, acc[i].z);
                acc[i].w = fmaf(h, w.w, acc[i].w);
            }
        }
#pragma unroll
        for (int kk = 0; kk < 4; ++kk) wv[kk] = wn[kk];
    }
#pragma unroll
    for (int i = 0; i < NS; ++i)
        if (i < n) *(float4*)(mup_kc + (size_t)bo[i] * OUTD + o) = acc[i];
}

// ------- mu partial: inline ballot grouping, NS-dispatched single-pass tiles (r4) ---
__global__ __launch_bounds__(256) void k_mu(const float* __restrict__ hmat,
                                            const float* __restrict__ subj_w,
                                            const int* __restrict__ sid,
                                            float* __restrict__ mup) {
    int o  = blockIdx.x * 1024 + threadIdx.x * 4;  // 8 ochunks
    int k0 = blockIdx.y * 128;                     // 8 kchunks
    int s  = blockIdx.z;                           // 8 subjects
    int lane = threadIdx.x & 63;
    int mysid = sid[lane];
    unsigned long long m = __ballot(mysid == s);
    int ns = __popcll(m);
    if (ns == 0) return;
    const float* wbase = subj_w + (size_t)s * HID * OUTD;
    float* mup_kc = mup + (size_t)blockIdx.y * BATCH * OUTD;
    unsigned long long mm = m;
    for (int base = 0; base < ns; base += 12) {
        int take = ns - base; if (take > 12) take = 12;
        int fb = (int)__builtin_ctzll(mm);
        int bo[12];
#pragma unroll
        for (int i = 0; i < 12; ++i) {
            bo[i] = (mm != 0ull) ? (int)__builtin_ctzll(mm) : fb;
            if (mm != 0ull) mm &= (mm - 1ull);
        }
        if (take <= 4)       mu_tile<4>(hmat, wbase, mup_kc, bo, take, k0, o);
        else if (take <= 8)  mu_tile<8>(hmat, wbase, mup_kc, bo, take, k0, o);
        else                 mu_tile<12>(hmat, wbase, mup_kc, bo, take, k0, o);
    }
}

// ------ log_var partial (NEW): 512 blocks (2/CU), f4 weights, k-transposed LDS -----
__global__ __launch_bounds__(256) void k_lv(const float* __restrict__ hmat,
                                            const float* __restrict__ lv_w,
                                            float* __restrict__ lvp) {
    __shared__ float hs[64][20];                   // [k][sample], 80B rows: 16B-aligned
    int o  = blockIdx.x * 1024 + threadIdx.x * 4;  // 8 ochunks, float4 (mu pattern)
    int k0 = blockIdx.y * 64;                      // 16 kchunks of 64
    int b0 = blockIdx.z * 16;                      // 4 bgroups of 16 samples
    {
        int k  = threadIdx.x & 63;                 // lanes 0..63 -> consecutive k
        int s4 = threadIdx.x >> 6;                 // 0..3 -> sample group
#pragma unroll
        for (int j = 0; j < 4; ++j)
            hs[k][s4 * 4 + j] = hmat[(size_t)(b0 + s4 * 4 + j) * HID + k0 + k];
    }
    __syncthreads();
    float4 acc[16];
#pragma unroll
    for (int i = 0; i < 16; ++i) acc[i] = make_float4(0.f, 0.f, 0.f, 0.f);
    const float* wp = lv_w + (size_t)k0 * OUTD + o;
#pragma unroll 4
    for (int k = 0; k < 64; ++k) {
        float4 w = *(const float4*)(wp + (size_t)k * OUTD);
        float4 h0 = *(const float4*)&hs[k][0];
        float4 h1 = *(const float4*)&hs[k][4];
        float4 h2 = *(const float4*)&hs[k][8];
        float4 h3 = *(const float4*)&hs[k][12];
        float hv[16] = {h0.x, h0.y, h0.z, h0.w, h1.x, h1.y, h1.z, h1.w,
                        h2.x, h2.y, h2.z, h2.w, h3.x, h3.y, h3.z, h3.w};
#pragma unroll
        for (int i = 0; i < 16; ++i) {
            acc[i].x = fmaf(hv[i], w.x, acc[i].x);
            acc[i].y = fmaf(hv[i], w.y, acc[i].y);
            acc[i].z = fmaf(hv[i], w.z, acc[i].z);
            acc[i].w = fmaf(hv[i], w.w, acc[i].w);
        }
    }
#pragma unroll
    for (int i = 0; i < 16; ++i)
        *(float4*)(lvp + ((size_t)blockIdx.y * BATCH + b0 + i) * OUTD + o) = acc[i];
}

// ------- combine: 8 mu partials + 16 lv partials, biases, clip, sample -------------
__global__ __launch_bounds__(256) void k_combine(const float* __restrict__ mup,
                                                 const float* __restrict__ lvp,
                                                 const float* __restrict__ eps,
                                                 const float* __restrict__ subj_b,
                                                 const float* __restrict__ lv_b,
                                                 const int* __restrict__ sid,
                                                 float* __restrict__ out) {
    int idx = (blockIdx.x * 256 + threadIdx.x) * 4;  // over 524288
    int b = idx >> 13;
    int o = idx & (OUTD - 1);
    float4 m = make_float4(0.f, 0.f, 0.f, 0.f);
    float4 l = make_float4(0.f, 0.f, 0.f, 0.f);
#pragma unroll
    for (int kc = 0; kc < 8; ++kc) {
        float4 t = *(const float4*)(mup + (size_t)kc * 524288 + idx);
        m.x += t.x; m.y += t.y; m.z += t.z; m.w += t.w;
    }
#pragma unroll
    for (int kc = 0; kc < 16; ++kc) {
        float4 u = *(const float4*)(lvp + (size_t)kc * 524288 + idx);
        l.x += u.x; l.y += u.y; l.z += u.z; l.w += u.w;
    }
    int s = sid[b];
    float4 sb = *(const float4*)(subj_b + s * OUTD + o);
    float4 lb = *(const float4*)(lv_b + o);
    m.x += sb.x; m.y += sb.y; m.z += sb.z; m.w += sb.w;
    l.x = fminf(fmaxf(l.x + lb.x, -10.f), 2.f);
    l.y = fminf(fmaxf(l.y + lb.y, -10.f), 2.f);
    l.z = fminf(fmaxf(l.z + lb.z, -10.f), 2.f);
    l.w = fminf(fmaxf(l.w + lb.w, -10.f), 2.f);
    float4 e = *(const float4*)(eps + idx);
    float4 x0;
    x0.x = m.x + e.x * __expf(0.5f * l.x);
    x0.y = m.y + e.y * __expf(0.5f * l.y);
    x0.z = m.z + e.z * __expf(0.5f * l.z);
    x0.w = m.w + e.w * __expf(0.5f * l.w);
    *(float4*)(out + idx) = x0;
    *(float4*)(out + 524288 + idx) = m;
    *(float4*)(out + 1048576 + idx) = l;
}

extern "C" void kernel_launch(void* const* d_in, const int* in_sizes, int n_in,
                              void* d_out, int out_size, void* d_ws, size_t ws_size,
                              hipStream_t stream) {
    const float* ctx    = (const float*)d_in[0];
    const int*   sid    = (const int*)  d_in[1];
    const float* eps    = (const float*)d_in[2];
    const float* w1     = (const float*)d_in[3];
    const float* b1     = (const float*)d_in[4];
    const float* w2     = (const float*)d_in[5];
    const float* b2     = (const float*)d_in[6];
    const float* subj_w = (const float*)d_in[7];
    const float* subj_b = (const float*)d_in[8];
    const float* lv_w   = (const float*)d_in[9];
    const float* lv_b   = (const float*)d_in[10];
    float* out = (float*)d_out;

    float* ws   = (float*)d_ws;
    float* pp   = ws + OFF_PP;
    float* p1   = ws + OFF_P1;
    float* p2   = ws + OFF_P2;
    float* hbuf = ws + OFF_H;
    float* mup  = ws + OFF_MUP;
    float* lvp  = ws + OFF_LVP;

    k_pool<<<dim3(BATCH, 16), 256, 0, stream>>>(ctx, pp);
    k_mlp1<<<dim3(4, 32, 2), 256, 0, stream>>>(pp, w1, p1);
    k_mlp2<<<dim3(4, 32, 2), 256, 0, stream>>>(p1, b1, w2, p2);
    k_red_bias<<<64, 256, 0, stream>>>(p2, b2, hbuf);
    k_mu<<<dim3(8, 8, NSUBJ), 256, 0, stream>>>(hbuf, subj_w, sid, mup);
    k_lv<<<dim3(8, 16, 4), 256, 0, stream>>>(hbuf, lv_w, lvp);
    k_combine<<<512, 256, 0, stream>>>(mup, lvp, eps, subj_b, lv_b, sid, out);
}

// Round 11
// 175.963 us; speedup vs baseline: 4.3253x; 1.0104x over previous
//
#include <hip/hip_runtime.h>
#include <math.h>

#define HID   1024
#define OUTD  8192
#define NSUBJ 8
#define BATCH 64
#define TLEN  512

// ws layout (float offsets)
#define OFF_PP    0u           // pool partials: 16*64*1024 = 1048576
#define OFF_P1    1048576u     // mlp1 partials: 32*64*1024 = 2097152
#define OFF_P2    3145728u     // mlp2 partials: 32*64*1024
#define OFF_H     5242880u     // 64*1024
#define OFF_MUP   5308416u     // mu partials: 8*64*8192 = 4194304
#define OFF_LVP   9502720u     // lv partials: 16*64*8192 = 8388608

// ---------------- mean pool: partial sums over 32-t chunks (r4) ----------------
__global__ __launch_bounds__(256) void k_pool(const float* __restrict__ ctx,
                                              float* __restrict__ pp) {
    int b  = blockIdx.x;   // 64
    int tc = blockIdx.y;   // 16
    int hid = threadIdx.x * 4;
    const float* base = ctx + ((size_t)b * TLEN + (size_t)tc * 32) * HID + hid;
    float4 acc = make_float4(0.f, 0.f, 0.f, 0.f);
#pragma unroll 8
    for (int t = 0; t < 32; ++t) {
        float4 v = *(const float4*)(base + (size_t)t * HID);
        acc.x += v.x; acc.y += v.y; acc.z += v.z; acc.w += v.w;
    }
    *(float4*)(pp + ((size_t)tc * BATCH + b) * HID + hid) = acc;
}

// -------- MLP layer 1: fused pool-reduce (LDS x-tile) + GEMM partial (r4 exact) -----
__global__ __launch_bounds__(256) void k_mlp1(const float* __restrict__ pp,
                                              const float* __restrict__ w1,
                                              float* __restrict__ p1) {
    __shared__ float xs[32][34];
    int j  = blockIdx.x * 256 + threadIdx.x;  // 4 jchunks
    int k0 = blockIdx.y * 32;                 // 32 kchunks
    int b0 = blockIdx.z * 32;                 // 2 bgroups
    {
        int bb = threadIdx.x >> 3;
        int kk = (threadIdx.x & 7) * 4;
        float4 s = make_float4(0.f, 0.f, 0.f, 0.f);
#pragma unroll
        for (int tc = 0; tc < 16; ++tc) {
            float4 v = *(const float4*)(pp + (size_t)tc * 65536 + (b0 + bb) * 1024 + k0 + kk);
            s.x += v.x; s.y += v.y; s.z += v.z; s.w += v.w;
        }
        const float inv = 1.0f / 512.0f;
        xs[bb][kk]     = s.x * inv;
        xs[bb][kk + 1] = s.y * inv;
        xs[bb][kk + 2] = s.z * inv;
        xs[bb][kk + 3] = s.w * inv;
    }
    __syncthreads();
    float acc[32];
#pragma unroll
    for (int i = 0; i < 32; ++i) acc[i] = 0.f;
    for (int kk = 0; kk < 32; kk += 2) {
        float wa = w1[(size_t)(k0 + kk) * HID + j];
        float wb = w1[(size_t)(k0 + kk + 1) * HID + j];
#pragma unroll
        for (int i = 0; i < 32; ++i) {
            acc[i] = fmaf(xs[i][kk], wa, acc[i]);
            acc[i] = fmaf(xs[i][kk + 1], wb, acc[i]);
        }
    }
    float* dst = p1 + (size_t)blockIdx.y * 65536;
#pragma unroll
    for (int i = 0; i < 32; ++i) dst[(b0 + i) * 1024 + j] = acc[i];
}

// -------- MLP layer 2: fused reduce+bias+exact-GELU + GEMM partial (r4 exact) -------
__global__ __launch_bounds__(256) void k_mlp2(const float* __restrict__ p1,
                                              const float* __restrict__ b1,
                                              const float* __restrict__ w2,
                                              float* __restrict__ p2) {
    __shared__ float xs[32][34];
    int j  = blockIdx.x * 256 + threadIdx.x;
    int k0 = blockIdx.y * 32;
    int b0 = blockIdx.z * 32;
    {
        int bb = threadIdx.x >> 3;
        int kk = (threadIdx.x & 7) * 4;
        float4 s = make_float4(0.f, 0.f, 0.f, 0.f);
#pragma unroll
        for (int kc = 0; kc < 32; ++kc) {
            float4 v = *(const float4*)(p1 + (size_t)kc * 65536 + (b0 + bb) * 1024 + k0 + kk);
            s.x += v.x; s.y += v.y; s.z += v.z; s.w += v.w;
        }
        float4 bbv = *(const float4*)(b1 + k0 + kk);
        s.x += bbv.x; s.y += bbv.y; s.z += bbv.z; s.w += bbv.w;
        const float r = 0.70710678118654752f;
        xs[bb][kk]     = 0.5f * s.x * (1.0f + erff(s.x * r));
        xs[bb][kk + 1] = 0.5f * s.y * (1.0f + erff(s.y * r));
        xs[bb][kk + 2] = 0.5f * s.z * (1.0f + erff(s.z * r));
        xs[bb][kk + 3] = 0.5f * s.w * (1.0f + erff(s.w * r));
    }
    __syncthreads();
    float acc[32];
#pragma unroll
    for (int i = 0; i < 32; ++i) acc[i] = 0.f;
    for (int kk = 0; kk < 32; kk += 2) {
        float wa = w2[(size_t)(k0 + kk) * HID + j];
        float wb = w2[(size_t)(k0 + kk + 1) * HID + j];
#pragma unroll
        for (int i = 0; i < 32; ++i) {
            acc[i] = fmaf(xs[i][kk], wa, acc[i]);
            acc[i] = fmaf(xs[i][kk + 1], wb, acc[i]);
        }
    }
    float* dst = p2 + (size_t)blockIdx.y * 65536;
#pragma unroll
    for (int i = 0; i < 32; ++i) dst[(b0 + i) * 1024 + j] = acc[i];
}

// ---------------- reduce 32 partials + bias -> hbuf (r4) ----------------
__global__ __launch_bounds__(256) void k_red_bias(const float* __restrict__ p,
                                                  const float* __restrict__ bias,
                                                  float* __restrict__ out) {
    int i = (blockIdx.x * 256 + threadIdx.x) * 4;  // 64 blocks
    int j = i & (HID - 1);
    float4 s = make_float4(0.f, 0.f, 0.f, 0.f);
#pragma unroll
    for (int kc = 0; kc < 32; ++kc) {
        float4 v = *(const float4*)(p + (size_t)kc * 65536 + i);
        s.x += v.x; s.y += v.y; s.z += v.z; s.w += v.w;
    }
    float4 bb = *(const float4*)(bias + j);
    s.x += bb.x; s.y += bb.y; s.z += bb.z; s.w += bb.w;
    *(float4*)(out + i) = s;
}

// -------- head tile body: NS samples, KLEN k-range, wv prefetch (r4-proven) --------
template <int NS, int KLEN>
__device__ __forceinline__ void mu_tile(const float* __restrict__ hmat,
                                        const float* __restrict__ wbase,
                                        float* __restrict__ dst_kc,
                                        const int* bo, int n, int k0, int o) {
    float4 acc[NS];
#pragma unroll
    for (int i = 0; i < NS; ++i) acc[i] = make_float4(0.f, 0.f, 0.f, 0.f);
    float4 wv[4];
#pragma unroll
    for (int kk = 0; kk < 4; ++kk)
        wv[kk] = *(const float4*)(wbase + (size_t)(k0 + kk) * OUTD + o);
    for (int k = k0; k < k0 + KLEN; k += 4) {
        float4 hv[NS];
#pragma unroll
        for (int i = 0; i < NS; ++i)
            hv[i] = *(const float4*)(hmat + bo[i] * HID + k);
        int kn = (k + 4 < k0 + KLEN) ? (k + 4) : k0;  // last-iter reload, harmless
        float4 wn[4];
#pragma unroll
        for (int kk = 0; kk < 4; ++kk)
            wn[kk] = *(const float4*)(wbase + (size_t)(kn + kk) * OUTD + o);
#pragma unroll
        for (int kk = 0; kk < 4; ++kk) {
            float4 w = wv[kk];
#pragma unroll
            for (int i = 0; i < NS; ++i) {
                float h = (kk == 0) ? hv[i].x : (kk == 1) ? hv[i].y
                        : (kk == 2) ? hv[i].z : hv[i].w;
                acc[i].x = fmaf(h, w.x, acc[i].x);
                acc[i].y = fmaf(h, w.y, acc[i].y);
                acc[i].z = fmaf(h, w.z, acc[i].z);
                acc[i].w = fmaf(h, w.w, acc[i].w);
            }
        }
#pragma unroll
        for (int kk = 0; kk < 4; ++kk) wv[kk] = wn[kk];
    }
#pragma unroll
    for (int i = 0; i < NS; ++i)
        if (i < n) *(float4*)(dst_kc + (size_t)bo[i] * OUTD + o) = acc[i];
}

// ------ merged heads: blk<512 = mu (r4-exact logic); blk>=512 = lv (bg=1 reg-tiled) -
__global__ __launch_bounds__(256) void k_head(const float* __restrict__ hbuf,
                                              const float* __restrict__ subj_w,
                                              const float* __restrict__ lv_w,
                                              const int* __restrict__ sid,
                                              float* __restrict__ mup,
                                              float* __restrict__ lvp) {
    int blk = blockIdx.x;
    int tid = threadIdx.x;
    if (blk < 512) {
        // ---- mu partial: och = blk&7, kc = (blk>>3)&7, s = blk>>6 ----
        int o  = (blk & 7) * 1024 + tid * 4;
        int k0 = ((blk >> 3) & 7) * 128;
        int s  = blk >> 6;
        int lane = tid & 63;
        int mysid = sid[lane];
        unsigned long long m = __ballot(mysid == s);
        int ns = __popcll(m);
        if (ns == 0) return;
        const float* wbase = subj_w + (size_t)s * HID * OUTD;
        float* mup_kc = mup + (size_t)((blk >> 3) & 7) * BATCH * OUTD;
        unsigned long long mm = m;
        for (int base = 0; base < ns; base += 12) {
            int take = ns - base; if (take > 12) take = 12;
            int fb = (int)__builtin_ctzll(mm);
            int bo[12];
#pragma unroll
            for (int i = 0; i < 12; ++i) {
                bo[i] = (mm != 0ull) ? (int)__builtin_ctzll(mm) : fb;
                if (mm != 0ull) mm &= (mm - 1ull);
            }
            if (take <= 4)       mu_tile<4, 128>(hbuf, wbase, mup_kc, bo, take, k0, o);
            else if (take <= 8)  mu_tile<8, 128>(hbuf, wbase, mup_kc, bo, take, k0, o);
            else                 mu_tile<12, 128>(hbuf, wbase, mup_kc, bo, take, k0, o);
        }
    } else {
        // ---- lv partial: u = blk-512; och = u&31 (o=256 f), kc = u>>5 (k=64) ----
        // 4 waves x 16 samples each; weight tile read once per block (L1-shared).
        int u   = blk - 512;
        int wid = tid >> 6;
        int lane = tid & 63;
        int o  = (u & 31) * 256 + lane * 4;
        int k0 = (u >> 5) * 64;
        int s0 = wid * 16;
        int bo[16];
#pragma unroll
        for (int i = 0; i < 16; ++i) bo[i] = s0 + i;
        float* lvp_kc = lvp + (size_t)(u >> 5) * BATCH * OUTD;
        mu_tile<16, 64>(hbuf, lv_w, lvp_kc, bo, 16, k0, o);
    }
}

// ------- combine: 8 mu partials + 16 lv partials, biases, clip, sample -------------
__global__ __launch_bounds__(256) void k_combine(const float* __restrict__ mup,
                                                 const float* __restrict__ lvp,
                                                 const float* __restrict__ eps,
                                                 const float* __restrict__ subj_b,
                                                 const float* __restrict__ lv_b,
                                                 const int* __restrict__ sid,
                                                 float* __restrict__ out) {
    int idx = (blockIdx.x * 256 + threadIdx.x) * 4;  // over 524288
    int b = idx >> 13;
    int o = idx & (OUTD - 1);
    float4 m = make_float4(0.f, 0.f, 0.f, 0.f);
    float4 l = make_float4(0.f, 0.f, 0.f, 0.f);
#pragma unroll
    for (int kc = 0; kc < 8; ++kc) {
        float4 t = *(const float4*)(mup + (size_t)kc * 524288 + idx);
        m.x += t.x; m.y += t.y; m.z += t.z; m.w += t.w;
    }
#pragma unroll
    for (int kc = 0; kc < 16; ++kc) {
        float4 u = *(const float4*)(lvp + (size_t)kc * 524288 + idx);
        l.x += u.x; l.y += u.y; l.z += u.z; l.w += u.w;
    }
    int s = sid[b];
    float4 sb = *(const float4*)(subj_b + s * OUTD + o);
    float4 lb = *(const float4*)(lv_b + o);
    m.x += sb.x; m.y += sb.y; m.z += sb.z; m.w += sb.w;
    l.x = fminf(fmaxf(l.x + lb.x, -10.f), 2.f);
    l.y = fminf(fmaxf(l.y + lb.y, -10.f), 2.f);
    l.z = fminf(fmaxf(l.z + lb.z, -10.f), 2.f);
    l.w = fminf(fmaxf(l.w + lb.w, -10.f), 2.f);
    float4 e = *(const float4*)(eps + idx);
    float4 x0;
    x0.x = m.x + e.x * __expf(0.5f * l.x);
    x0.y = m.y + e.y * __expf(0.5f * l.y);
    x0.z = m.z + e.z * __expf(0.5f * l.z);
    x0.w = m.w + e.w * __expf(0.5f * l.w);
    *(float4*)(out + idx) = x0;
    *(float4*)(out + 524288 + idx) = m;
    *(float4*)(out + 1048576 + idx) = l;
}

extern "C" void kernel_launch(void* const* d_in, const int* in_sizes, int n_in,
                              void* d_out, int out_size, void* d_ws, size_t ws_size,
                              hipStream_t stream) {
    const float* ctx    = (const float*)d_in[0];
    const int*   sid    = (const int*)  d_in[1];
    const float* eps    = (const float*)d_in[2];
    const float* w1     = (const float*)d_in[3];
    const float* b1     = (const float*)d_in[4];
    const float* w2     = (const float*)d_in[5];
    const float* b2     = (const float*)d_in[6];
    const float* subj_w = (const float*)d_in[7];
    const float* subj_b = (const float*)d_in[8];
    const float* lv_w   = (const float*)d_in[9];
    const float* lv_b   = (const float*)d_in[10];
    float* out = (float*)d_out;

    float* ws   = (float*)d_ws;
    float* pp   = ws + OFF_PP;
    float* p1   = ws + OFF_P1;
    float* p2   = ws + OFF_P2;
    float* hbuf = ws + OFF_H;
    float* mup  = ws + OFF_MUP;
    float* lvp  = ws + OFF_LVP;

    k_pool<<<dim3(BATCH, 16), 256, 0, stream>>>(ctx, pp);
    k_mlp1<<<dim3(4, 32, 2), 256, 0, stream>>>(pp, w1, p1);
    k_mlp2<<<dim3(4, 32, 2), 256, 0, stream>>>(p1, b1, w2, p2);
    k_red_bias<<<64, 256, 0, stream>>>(p2, b2, hbuf);
    k_head<<<1024, 256, 0, stream>>>(hbuf, subj_w, lv_w, sid, mup, lvp);
    k_combine<<<512, 256, 0, stream>>>(mup, lvp, eps, subj_b, lv_b, sid, out);
}